// Round 7
// baseline (384.751 us; speedup 1.0000x reference)
//
#include <hip/hip_runtime.h>
#include <stdint.h>

#define BATCH_N   131072
#define HID       256
#define SPIKE_DIM 128
#define COORD_DIM 64
#define IN_DIM    192
#define STEPS     25
#define TILE      32
#define BLOCK     256

typedef float f4  __attribute__((ext_vector_type(4)));
typedef short bf8 __attribute__((ext_vector_type(8)));
typedef unsigned short us4 __attribute__((ext_vector_type(4)));

// ws layout (float offsets):
//   W0b  [256][192] bf16   floats 0..24575   (49152 ushorts)
//   W1T  [256][256] fp32   at 24576
//   WoT  [256][64]  fp32   at 90112
//   CMX  [256]      fp32   at 106496   colmax[j] = max_i max(W1[i][j],0)
#define W1T_OFF 24576
#define WOT_OFF 90112
#define CMX_OFF 106496

static __device__ __forceinline__ unsigned short f2bf(float f) {
  union { float f; unsigned u; } v; v.f = f;
  unsigned r = v.u + 0x7FFF + ((v.u >> 16) & 1);   // RNE
  return (unsigned short)(r >> 16);
}

__global__ __launch_bounds__(256)
void prep_kernel(const float* __restrict__ W0,
                 const float* __restrict__ W1,
                 const float* __restrict__ Wout,
                 float* __restrict__ ws) {
  int idx = blockIdx.x * 256 + threadIdx.x;
  if (idx < HID*IN_DIM) {               // W0b elementwise (row-major, k-contig)
    ((unsigned short*)ws)[idx] = f2bf(W0[idx]);
  }
  int i1 = idx - HID*IN_DIM;            // W1T[j][i] = W1[i][j]
  if (i1 >= 0 && i1 < HID*HID) {
    int j = i1 >> 8, i = i1 & 255;
    ws[W1T_OFF + i1] = W1[i*HID + j];
  }
  int i2 = idx - (HID*IN_DIM + HID*HID);// WoT[k][c] = Wout[128+c][k]
  if (i2 >= 0 && i2 < HID*COORD_DIM) {
    int k = i2 >> 6, c = i2 & 63;
    ws[WOT_OFF + i2] = Wout[(SPIKE_DIM + c)*HID + k];
  }
  if (blockIdx.x == 0) {                // colmax[j] (>=0 by init, >= all W1[.][j])
    int j = threadIdx.x;
    float m = 0.f;
    for (int i = 0; i < HID; ++i)
      m = fmaxf(m, W1[i*HID + j]);
    ws[CMX_OFF + j] = m;
  }
}

__global__ __launch_bounds__(BLOCK)
void snn_kernel(const float* __restrict__ spk,
                const float* __restrict__ crd,
                const float* __restrict__ W0,
                const float* __restrict__ b0,
                const float* __restrict__ b1,
                const float* __restrict__ bout,
                const float* __restrict__ ws,
                float* __restrict__ out) {
  // LDS: xb 12800 B + bsum 256 B = ~12.9 KB; VGPR ~48 -> up to 8 blocks/CU
  // resident (32 waves). Round-7 experiment: same per-wave work as round 6,
  // 4x more independent blocks for latency hiding + smaller tail.
  __shared__ unsigned short xb[TILE*200];   // x tile, bf16, stride 200
  __shared__ float bsum[TILE*2];            // per-element colmax-sum, [row][nhalf]

  const int tid  = threadIdx.x;
  const int lane = tid & 63;
  const int wv   = tid >> 6;            // wave 0..3
  const int quad = lane >> 4;
  const int l15  = lane & 15;
  const int e0   = blockIdx.x * TILE;
  const int i4   = lane * 4;            // phase-B: this lane's 4 neurons

  // ---- stage x tile as bf16 into LDS ----
  {
    const f4* sp4 = (const f4*)(spk + (size_t)e0 * SPIKE_DIM);
    for (int t = tid; t < TILE*SPIKE_DIM/4; t += BLOCK) {
      int e = t >> 5, j = (t & 31) * 4;
      f4 v = __builtin_nontemporal_load(&sp4[t]);
      us4 h; h.x = f2bf(v.x); h.y = f2bf(v.y); h.z = f2bf(v.z); h.w = f2bf(v.w);
      *(us4*)&xb[e*200 + j] = h;
    }
    const f4* cr4 = (const f4*)(crd + (size_t)e0 * COORD_DIM);
    for (int t = tid; t < TILE*COORD_DIM/4; t += BLOCK) {
      int e = t >> 4, j = SPIKE_DIM + (t & 15) * 4;
      f4 v = __builtin_nontemporal_load(&cr4[t]);
      us4 h; h.x = f2bf(v.x); h.y = f2bf(v.y); h.z = f2bf(v.z); h.w = f2bf(v.w);
      *(us4*)&xb[e*200 + j] = h;
    }
  }
  __syncthreads();

  // ---- Phase A: c0 ~= x @ W0^T via bf16 MFMA (16x16x32) ----
  // wave tile: 16 elements (msub 0..1) x 128 neurons (nhalf 0..1)
  const int msub  = wv >> 1;
  const int nhalf = wv & 1;
  const unsigned short* W0b = (const unsigned short*)ws;  // [256][192]

  f4 acc[8];
  #pragma unroll
  for (int n = 0; n < 8; ++n) { acc[n].x = acc[n].y = acc[n].z = acc[n].w = 0.f; }

  #pragma unroll
  for (int kc = 0; kc < IN_DIM/32; ++kc) {
    bf8 a = *(const bf8*)&xb[(msub*16 + l15)*200 + kc*32 + quad*8];
    #pragma unroll
    for (int n = 0; n < 8; ++n) {
      bf8 b = *(const bf8*)&W0b[(size_t)(nhalf*128 + n*16 + l15)*IN_DIM + kc*32 + quad*8];
      acc[n] = __builtin_amdgcn_mfma_f32_16x16x32_bf16(a, b, acc[n], 0, 0, 0);
    }
  }

  // ---- epilogue: colmax-weighted active-set sums per element row ----
  // C/D layout: col(neuron)=l15, row(element)=msub*16+quad*4+reg.
  // Mask at 0.90 on pre-bf16 fp32 values (superset of exact {c0>=0.96}).
  // acc dies HERE (round-3 lesson).
  {
    const float* cmax = ws + CMX_OFF;
    float p0 = 0.f, p1 = 0.f, p2 = 0.f, p3 = 0.f;
    #pragma unroll
    for (int n = 0; n < 8; ++n) {
      const int neuron = nhalf*128 + n*16 + l15;
      const float bias = b0[neuron];
      const float cm   = cmax[neuron];
      p0 += (acc[n].x + bias >= 0.90f) ? cm : 0.f;
      p1 += (acc[n].y + bias >= 0.90f) ? cm : 0.f;
      p2 += (acc[n].z + bias >= 0.90f) ? cm : 0.f;
      p3 += (acc[n].w + bias >= 0.90f) ? cm : 0.f;
    }
    #pragma unroll
    for (int m = 1; m <= 8; m <<= 1) {      // butterfly over l15 only
      p0 += __shfl_xor(p0, m, 64);
      p1 += __shfl_xor(p1, m, 64);
      p2 += __shfl_xor(p2, m, 64);
      p3 += __shfl_xor(p3, m, 64);
    }
    if (l15 == 0) {
      const int erow = msub*16 + quad*4;
      bsum[(erow+0)*2 + nhalf] = p0;
      bsum[(erow+1)*2 + nhalf] = p1;
      bsum[(erow+2)*2 + nhalf] = p2;
      bsum[(erow+3)*2 + nhalf] = p3;
    }
  }
  __syncthreads();

  // ---- Phase B ----
  const float* W1T = ws + W1T_OFF;
  const float* WoT = ws + WOT_OFF;
  f4 b0v = *(const f4*)&b0[i4];
  f4 b1v = *(const f4*)&b1[i4];
  float bc = bout[SPIKE_DIM + lane];
  const int eb = wv * 8;

  // maxb1 across all 256 neurons (bitwise-identical in every lane)
  float mb = fmaxf(fmaxf(b1v.x, b1v.y), fmaxf(b1v.z, b1v.w));
  #pragma unroll
  for (int m = 1; m <= 32; m <<= 1) mb = fmaxf(mb, __shfl_xor(mb, m, 64));

  #pragma clang loop unroll(disable)
  for (int ee = 0; ee < 8; ++ee) {
    const int el = eb + ee;
    const int e  = e0 + el;
    // sufficient bound: any c1_t(i) <= maxb1 + sum_{j in A} colmax[j]
    const float tot = bsum[el*2] + bsum[el*2+1] + mb;   // wave-uniform

    if (tot < 0.98f) {
      // fast path: provably no layer-1 spikes -> exact outputs (0, b_out)
      f4 z; z.x = z.y = z.z = z.w = 0.f;
      __builtin_nontemporal_store(z, (f4*)&out[(size_t)e*HID + i4]);
      __builtin_nontemporal_store(bc,
          &out[(size_t)BATCH_N*HID + (size_t)e*COORD_DIM + lane]);
    } else {
      // ---- exact c0 recompute from global x, W0 (serial FMA) ----
      float cx = 0.f, cy = 0.f, cz = 0.f, cw = 0.f;
      const float* r0 = W0 + (size_t)(i4+0)*IN_DIM;
      const float* r1 = W0 + (size_t)(i4+1)*IN_DIM;
      const float* r2 = W0 + (size_t)(i4+2)*IN_DIM;
      const float* r3 = W0 + (size_t)(i4+3)*IN_DIM;
      const float* xs_ = spk + (size_t)e*SPIKE_DIM;
      const float* xc_ = crd + (size_t)e*COORD_DIM;
      for (int j = 0; j < SPIKE_DIM; ++j) {
        float xj = xs_[j];
        cx = fmaf(xj, r0[j], cx); cy = fmaf(xj, r1[j], cy);
        cz = fmaf(xj, r2[j], cz); cw = fmaf(xj, r3[j], cw);
      }
      for (int j = 0; j < COORD_DIM; ++j) {
        float xj = xc_[j];
        cx = fmaf(xj, r0[SPIKE_DIM+j], cx); cy = fmaf(xj, r1[SPIKE_DIM+j], cy);
        cz = fmaf(xj, r2[SPIKE_DIM+j], cz); cw = fmaf(xj, r3[SPIKE_DIM+j], cw);
      }
      const float c0x = cx + b0v.x, c0y = cy + b0v.y;
      const float c0z = cz + b0v.z, c0w = cw + b0v.w;

      // per-i bound over exact active set {c0 >= 0.96}
      unsigned long long a0 = __ballot(c0x >= 0.96f);
      unsigned long long a1 = __ballot(c0y >= 0.96f);
      unsigned long long a2 = __ballot(c0z >= 0.96f);
      unsigned long long a3 = __ballot(c0w >= 0.96f);

      f4 bnd = b1v;
      unsigned long long mm;
      #define BPROCQ(MASK, Q)                                   \
        mm = (MASK);                                            \
        while (mm) {                                            \
          int l = __builtin_ctzll(mm); mm &= mm - 1;            \
          f4 wv_ = *(const f4*)&W1T[(l*4 + (Q))*HID + i4];      \
          bnd.x += fmaxf(wv_.x, 0.f);                           \
          bnd.y += fmaxf(wv_.y, 0.f);                           \
          bnd.z += fmaxf(wv_.z, 0.f);                           \
          bnd.w += fmaxf(wv_.w, 0.f);                           \
        }
      BPROCQ(a0, 0)
      BPROCQ(a1, 1)
      BPROCQ(a2, 2)
      BPROCQ(a3, 3)
      #undef BPROCQ

      bool threat = (bnd.x >= 0.98f) | (bnd.y >= 0.98f) |
                    (bnd.z >= 0.98f) | (bnd.w >= 0.98f);

      if (__ballot(threat) == 0ull) {
        f4 z; z.x = z.y = z.z = z.w = 0.f;
        __builtin_nontemporal_store(z, (f4*)&out[(size_t)e*HID + i4]);
        __builtin_nontemporal_store(bc,
            &out[(size_t)BATCH_N*HID + (size_t)e*COORD_DIM + lane]);
      } else {
        // ---- honest 25-step simulation (round-2 verbatim, exact) ----
        float v0x=0.f, v0y=0.f, v0z=0.f, v0w=0.f;
        float v1x=0.f, v1y=0.f, v1z=0.f, v1w=0.f;
        float s1x=0.f, s1y=0.f, s1z=0.f, s1w=0.f;

        for (int t = 0; t < STEPS; ++t) {
          bool sp;
          unsigned long long m0, m1, m2, m3;
          v0x = __fmul_rn(0.7f, v0x) + __fmul_rn(0.3f, c0x);
          sp = (v0x >= 1.0f); m0 = __ballot(sp); if (sp) v0x = 0.f;
          v0y = __fmul_rn(0.7f, v0y) + __fmul_rn(0.3f, c0y);
          sp = (v0y >= 1.0f); m1 = __ballot(sp); if (sp) v0y = 0.f;
          v0z = __fmul_rn(0.7f, v0z) + __fmul_rn(0.3f, c0z);
          sp = (v0z >= 1.0f); m2 = __ballot(sp); if (sp) v0z = 0.f;
          v0w = __fmul_rn(0.7f, v0w) + __fmul_rn(0.3f, c0w);
          sp = (v0w >= 1.0f); m3 = __ballot(sp); if (sp) v0w = 0.f;

          float c1x = b1v.x, c1y = b1v.y, c1z = b1v.z, c1w = b1v.w;
          f4 wcur; wcur.x = wcur.y = wcur.z = wcur.w = 0.f;
          int have = 0;
          #define PROCQ(MASK, Q)                                                  \
            mm = (MASK);                                                          \
            while (mm) {                                                          \
              int l = __builtin_ctzll(mm); mm &= mm - 1;                          \
              f4 wn = *(const f4*)&W1T[(l*4 + (Q))*HID + i4];                     \
              if (have) { c1x += wcur.x; c1y += wcur.y; c1z += wcur.z; c1w += wcur.w; } \
              wcur = wn; have = 1;                                                \
            }
          PROCQ(m0, 0)
          PROCQ(m1, 1)
          PROCQ(m2, 2)
          PROCQ(m3, 3)
          #undef PROCQ
          if (have) { c1x += wcur.x; c1y += wcur.y; c1z += wcur.z; c1w += wcur.w; }

          v1x = __fmul_rn(0.7f, v1x) + __fmul_rn(0.3f, c1x);
          sp = (v1x >= 1.0f); s1x = sp ? 1.f : 0.f; if (sp) v1x = 0.f;
          v1y = __fmul_rn(0.7f, v1y) + __fmul_rn(0.3f, c1y);
          sp = (v1y >= 1.0f); s1y = sp ? 1.f : 0.f; if (sp) v1y = 0.f;
          v1z = __fmul_rn(0.7f, v1z) + __fmul_rn(0.3f, c1z);
          sp = (v1z >= 1.0f); s1z = sp ? 1.f : 0.f; if (sp) v1z = 0.f;
          v1w = __fmul_rn(0.7f, v1w) + __fmul_rn(0.3f, c1w);
          sp = (v1w >= 1.0f); s1w = sp ? 1.f : 0.f; if (sp) v1w = 0.f;
        }

        f4 res; res.x = s1x; res.y = s1y; res.z = s1z; res.w = s1w;
        __builtin_nontemporal_store(res, (f4*)&out[(size_t)e*HID + i4]);

        unsigned long long f0 = __ballot(s1x > 0.5f);
        unsigned long long f1 = __ballot(s1y > 0.5f);
        unsigned long long f2 = __ballot(s1z > 0.5f);
        unsigned long long f3 = __ballot(s1w > 0.5f);
        float cacc = bc;
        #define CPROCQ(MASK, Q)                                 \
          mm = (MASK);                                          \
          while (mm) {                                          \
            int l = __builtin_ctzll(mm); mm &= mm - 1;          \
            cacc += WoT[(l*4 + (Q))*COORD_DIM + lane];          \
          }
        CPROCQ(f0, 0)
        CPROCQ(f1, 1)
        CPROCQ(f2, 2)
        CPROCQ(f3, 3)
        #undef CPROCQ
        __builtin_nontemporal_store(cacc,
            &out[(size_t)BATCH_N*HID + (size_t)e*COORD_DIM + lane]);
      }
    }
  }
}

extern "C" void kernel_launch(void* const* d_in, const int* in_sizes, int n_in,
                              void* d_out, int out_size, void* d_ws, size_t ws_size,
                              hipStream_t stream) {
  (void)in_sizes; (void)n_in; (void)out_size; (void)ws_size;
  const float* spk = (const float*)d_in[0];
  const float* crd = (const float*)d_in[1];
  const float* W0  = (const float*)d_in[2];
  const float* b0  = (const float*)d_in[3];
  const float* W1  = (const float*)d_in[4];
  const float* b1  = (const float*)d_in[5];
  const float* Wo  = (const float*)d_in[6];
  const float* bo  = (const float*)d_in[7];
  float* ws  = (float*)d_ws;
  float* out = (float*)d_out;

  hipLaunchKernelGGL(prep_kernel, dim3(512), dim3(256), 0, stream, W0, W1, Wo, ws);
  hipLaunchKernelGGL(snn_kernel, dim3(BATCH_N/TILE), dim3(BLOCK), 0, stream,
                     spk, crd, W0, b0, b1, bo, ws, out);
}

// Round 9
// 370.836 us; speedup vs baseline: 1.0375x; 1.0375x over previous
//
#include <hip/hip_runtime.h>
#include <stdint.h>

#define BATCH_N   131072
#define HID       256
#define SPIKE_DIM 128
#define COORD_DIM 64
#define IN_DIM    192
#define STEPS     25
#define TILE      64
#define BLOCK     256
#define N_ACT4    (BATCH_N*HID/4)       // 8388608 f4 zeros
#define N_CRD4    (BATCH_N*COORD_DIM/4) // 2097152 f4 pattern

typedef float f4  __attribute__((ext_vector_type(4)));
typedef short bf8 __attribute__((ext_vector_type(8)));
typedef unsigned short us4 __attribute__((ext_vector_type(4)));

// ws layout (float offsets):
//   W0b  [256][192] bf16   floats 0..24575
//   W1T  [256][256] fp32   at 24576
//   WoT  [256][64]  fp32   at 90112
//   CMX  [256]      fp32   at 106496   colmax[j] = max_i max(W1[i][j],0)
#define W1T_OFF 24576
#define WOT_OFF 90112
#define CMX_OFF 106496

static __device__ __forceinline__ unsigned short f2bf(float f) {
  union { float f; unsigned u; } v; v.f = f;
  unsigned r = v.u + 0x7FFF + ((v.u >> 16) & 1);   // RNE
  return (unsigned short)(r >> 16);
}

// One kernel: prep (transposes, bf16 W0, colmax) + default-output streaming.
__global__ __launch_bounds__(256)
void init_kernel(const float* __restrict__ W0,
                 const float* __restrict__ W1,
                 const float* __restrict__ Wout,
                 const float* __restrict__ bout,
                 float* __restrict__ ws,
                 float* __restrict__ out) {
  const int tid = threadIdx.x;
  const int idx = blockIdx.x * 256 + tid;

  // ---- prep section (first 512 blocks' index range) ----
  if (idx < HID*IN_DIM) {               // W0b elementwise (row-major, k-contig)
    ((unsigned short*)ws)[idx] = f2bf(W0[idx]);
  }
  int i1 = idx - HID*IN_DIM;            // W1T[j][i] = W1[i][j]
  if (i1 >= 0 && i1 < HID*HID) {
    int j = i1 >> 8, i = i1 & 255;
    ws[W1T_OFF + i1] = W1[i*HID + j];
  }
  int i2 = idx - (HID*IN_DIM + HID*HID);// WoT[k][c] = Wout[128+c][k]
  if (i2 >= 0 && i2 < HID*COORD_DIM) {
    int k = i2 >> 6, c = i2 & 63;
    ws[WOT_OFF + i2] = Wout[(SPIKE_DIM + c)*HID + k];
  }
  if (blockIdx.x == 0) {                // colmax[j], 4-way ILP (no serial chain)
    float m0 = 0.f, m1 = 0.f, m2 = 0.f, m3 = 0.f;
    #pragma unroll 4
    for (int i = 0; i < HID; i += 4) {
      m0 = fmaxf(m0, W1[(i+0)*HID + tid]);
      m1 = fmaxf(m1, W1[(i+1)*HID + tid]);
      m2 = fmaxf(m2, W1[(i+2)*HID + tid]);
      m3 = fmaxf(m3, W1[(i+3)*HID + tid]);
    }
    ws[CMX_OFF + tid] = fmaxf(fmaxf(m0, m1), fmaxf(m2, m3));
  }

  // ---- default outputs: action = 0, coords = b_out[128:] pattern ----
  const size_t stride = (size_t)gridDim.x * 256;
  f4 z; z.x = z.y = z.z = z.w = 0.f;
  f4* outA = (f4*)out;
  for (size_t t = idx; t < (size_t)N_ACT4; t += stride)
    __builtin_nontemporal_store(z, outA + t);
  // stride % 16 == 0 -> (t & 15) is constant per thread == tid & 15
  f4 myc = *(const f4*)&bout[SPIKE_DIM + (tid & 15)*4];
  f4* outC = (f4*)(out + (size_t)BATCH_N*HID);
  for (size_t t = idx; t < (size_t)N_CRD4; t += stride)
    __builtin_nontemporal_store(myc, outC + t);
}

__global__ __launch_bounds__(BLOCK)
void snn_kernel(const float* __restrict__ spk,
                const float* __restrict__ crd,
                const float* __restrict__ W0,
                const float* __restrict__ b0,
                const float* __restrict__ b1,
                const float* __restrict__ bout,
                const float* __restrict__ ws,
                float* __restrict__ out) {
  // Detector kernel: fast path stores NOTHING (defaults already written by
  // init_kernel, stream-ordered). One wave owns 16 elements x 256 neurons ->
  // single barrier, wave-local threat sums via shuffles.
  __shared__ unsigned short xb[TILE*200];   // x tile bf16, stride 200 (25600 B)
  __shared__ float cms[HID];                // colmax     (1024 B)
  __shared__ float thr[HID];                // 0.90 - b0  (1024 B)

  const int tid  = threadIdx.x;
  const int lane = tid & 63;
  const int wv   = tid >> 6;            // wave 0..3; owns elements [wv*16,+16)
  const int quad = lane >> 4;
  const int l15  = lane & 15;
  const int e0   = blockIdx.x * TILE;
  const int i4   = lane * 4;

  // ---- stage thresholds + x tile ----
  if (tid < 64) {
    *(f4*)&cms[tid*4] = *(const f4*)&ws[CMX_OFF + tid*4];
  } else if (tid < 128) {
    int j = (tid - 64) * 4;
    f4 b = *(const f4*)&b0[j];
    f4 t_; t_.x = 0.90f - b.x; t_.y = 0.90f - b.y;
           t_.z = 0.90f - b.z; t_.w = 0.90f - b.w;
    *(f4*)&thr[j] = t_;
  }
  {
    const f4* sp4 = (const f4*)(spk + (size_t)e0 * SPIKE_DIM);
    for (int t = tid; t < TILE*SPIKE_DIM/4; t += BLOCK) {
      int e = t >> 5, j = (t & 31) * 4;
      f4 v = __builtin_nontemporal_load(&sp4[t]);
      us4 h; h.x = f2bf(v.x); h.y = f2bf(v.y); h.z = f2bf(v.z); h.w = f2bf(v.w);
      *(us4*)&xb[e*200 + j] = h;
    }
    const f4* cr4 = (const f4*)(crd + (size_t)e0 * COORD_DIM);
    for (int t = tid; t < TILE*COORD_DIM/4; t += BLOCK) {
      int e = t >> 4, j = SPIKE_DIM + (t & 15) * 4;
      f4 v = __builtin_nontemporal_load(&cr4[t]);
      us4 h; h.x = f2bf(v.x); h.y = f2bf(v.y); h.z = f2bf(v.z); h.w = f2bf(v.w);
      *(us4*)&xb[e*200 + j] = h;
    }
  }
  __syncthreads();

  // ---- Phase A: 16 elements x 256 neurons per wave, bf16 MFMA 16x16x32 ----
  const unsigned short* W0b = (const unsigned short*)ws;  // [256][192]
  f4 acc[16];
  #pragma unroll
  for (int n = 0; n < 16; ++n) { acc[n].x = acc[n].y = acc[n].z = acc[n].w = 0.f; }

  #pragma clang loop unroll(disable)
  for (int kc = 0; kc < IN_DIM/32; ++kc) {
    bf8 a = *(const bf8*)&xb[(wv*16 + l15)*200 + kc*32 + quad*8];
    #pragma unroll
    for (int n = 0; n < 16; ++n) {
      bf8 b = *(const bf8*)&W0b[(size_t)(n*16 + l15)*IN_DIM + kc*32 + quad*8];
      acc[n] = __builtin_amdgcn_mfma_f32_16x16x32_bf16(a, b, acc[n], 0, 0, 0);
    }
  }

  // ---- epilogue: colmax-weighted active-set sums (acc dies here) ----
  // C/D: col(neuron)=l15, row(element)=quad*4+reg. Mask acc>=thr[j]
  // (== acc+b0 >= 0.90 within 1 ulp) is a superset of exact {c0>=0.96}.
  float p0 = 0.f, p1 = 0.f, p2 = 0.f, p3 = 0.f;
  #pragma unroll
  for (int n = 0; n < 16; ++n) {
    const int neuron = n*16 + l15;
    const float th = thr[neuron], cm = cms[neuron];
    p0 += (acc[n].x >= th) ? cm : 0.f;
    p1 += (acc[n].y >= th) ? cm : 0.f;
    p2 += (acc[n].z >= th) ? cm : 0.f;
    p3 += (acc[n].w >= th) ? cm : 0.f;
  }
  #pragma unroll
  for (int m = 1; m <= 8; m <<= 1) {        // butterfly within l15 group
    p0 += __shfl_xor(p0, m, 64);
    p1 += __shfl_xor(p1, m, 64);
    p2 += __shfl_xor(p2, m, 64);
    p3 += __shfl_xor(p3, m, 64);
  }

  // maxb1 (bitwise-identical in every lane)
  f4 b1v = *(const f4*)&b1[i4];
  float mb = fmaxf(fmaxf(b1v.x, b1v.y), fmaxf(b1v.z, b1v.w));
  #pragma unroll
  for (int m = 1; m <= 32; m <<= 1) mb = fmaxf(mb, __shfl_xor(mb, m, 64));

  // ---- Phase B: wave-uniform threat check; store only on threat ----
  const float* W1T = ws + W1T_OFF;
  const float* WoT = ws + WOT_OFF;

  #pragma clang loop unroll(disable)
  for (int el = 0; el < 16; ++el) {
    const int q = el >> 2, r = el & 3;
    float pr = (r == 0) ? p0 : ((r == 1) ? p1 : ((r == 2) ? p2 : p3));
    const float tot = __shfl(pr, q*16, 64) + mb;   // wave-uniform

    if (tot >= 0.98f) {
      // ---- rare slow path: exact recompute + honest sim + stores ----
      const int e = e0 + wv*16 + el;
      f4 b0v = *(const f4*)&b0[i4];
      float bc = bout[SPIKE_DIM + lane];

      float cx = 0.f, cy = 0.f, cz = 0.f, cw = 0.f;
      const float* r0 = W0 + (size_t)(i4+0)*IN_DIM;
      const float* r1 = W0 + (size_t)(i4+1)*IN_DIM;
      const float* r2 = W0 + (size_t)(i4+2)*IN_DIM;
      const float* r3 = W0 + (size_t)(i4+3)*IN_DIM;
      const float* xs_ = spk + (size_t)e*SPIKE_DIM;
      const float* xc_ = crd + (size_t)e*COORD_DIM;
      for (int j = 0; j < SPIKE_DIM; ++j) {
        float xj = xs_[j];
        cx = fmaf(xj, r0[j], cx); cy = fmaf(xj, r1[j], cy);
        cz = fmaf(xj, r2[j], cz); cw = fmaf(xj, r3[j], cw);
      }
      for (int j = 0; j < COORD_DIM; ++j) {
        float xj = xc_[j];
        cx = fmaf(xj, r0[SPIKE_DIM+j], cx); cy = fmaf(xj, r1[SPIKE_DIM+j], cy);
        cz = fmaf(xj, r2[SPIKE_DIM+j], cz); cw = fmaf(xj, r3[SPIKE_DIM+j], cw);
      }
      const float c0x = cx + b0v.x, c0y = cy + b0v.y;
      const float c0z = cz + b0v.z, c0w = cw + b0v.w;

      // per-i bound over exact active set {c0 >= 0.96}
      unsigned long long a0 = __ballot(c0x >= 0.96f);
      unsigned long long a1 = __ballot(c0y >= 0.96f);
      unsigned long long a2 = __ballot(c0z >= 0.96f);
      unsigned long long a3 = __ballot(c0w >= 0.96f);

      f4 bnd = b1v;
      unsigned long long mm;
      #define BPROCQ(MASK, Q)                                   \
        mm = (MASK);                                            \
        while (mm) {                                            \
          int l = __builtin_ctzll(mm); mm &= mm - 1;            \
          f4 wv_ = *(const f4*)&W1T[(l*4 + (Q))*HID + i4];      \
          bnd.x += fmaxf(wv_.x, 0.f);                           \
          bnd.y += fmaxf(wv_.y, 0.f);                           \
          bnd.z += fmaxf(wv_.z, 0.f);                           \
          bnd.w += fmaxf(wv_.w, 0.f);                           \
        }
      BPROCQ(a0, 0)
      BPROCQ(a1, 1)
      BPROCQ(a2, 2)
      BPROCQ(a3, 3)
      #undef BPROCQ

      bool threat = (bnd.x >= 0.98f) | (bnd.y >= 0.98f) |
                    (bnd.z >= 0.98f) | (bnd.w >= 0.98f);

      if (__ballot(threat) != 0ull) {
        // honest 25-step simulation (round-2 verbatim, exact)
        float v0x=0.f, v0y=0.f, v0z=0.f, v0w=0.f;
        float v1x=0.f, v1y=0.f, v1z=0.f, v1w=0.f;
        float s1x=0.f, s1y=0.f, s1z=0.f, s1w=0.f;

        for (int t = 0; t < STEPS; ++t) {
          bool sp;
          unsigned long long m0, m1, m2, m3;
          v0x = __fmul_rn(0.7f, v0x) + __fmul_rn(0.3f, c0x);
          sp = (v0x >= 1.0f); m0 = __ballot(sp); if (sp) v0x = 0.f;
          v0y = __fmul_rn(0.7f, v0y) + __fmul_rn(0.3f, c0y);
          sp = (v0y >= 1.0f); m1 = __ballot(sp); if (sp) v0y = 0.f;
          v0z = __fmul_rn(0.7f, v0z) + __fmul_rn(0.3f, c0z);
          sp = (v0z >= 1.0f); m2 = __ballot(sp); if (sp) v0z = 0.f;
          v0w = __fmul_rn(0.7f, v0w) + __fmul_rn(0.3f, c0w);
          sp = (v0w >= 1.0f); m3 = __ballot(sp); if (sp) v0w = 0.f;

          float c1x = b1v.x, c1y = b1v.y, c1z = b1v.z, c1w = b1v.w;
          f4 wcur; wcur.x = wcur.y = wcur.z = wcur.w = 0.f;
          int have = 0;
          #define PROCQ(MASK, Q)                                                  \
            mm = (MASK);                                                          \
            while (mm) {                                                          \
              int l = __builtin_ctzll(mm); mm &= mm - 1;                          \
              f4 wn = *(const f4*)&W1T[(l*4 + (Q))*HID + i4];                     \
              if (have) { c1x += wcur.x; c1y += wcur.y; c1z += wcur.z; c1w += wcur.w; } \
              wcur = wn; have = 1;                                                \
            }
          PROCQ(m0, 0)
          PROCQ(m1, 1)
          PROCQ(m2, 2)
          PROCQ(m3, 3)
          #undef PROCQ
          if (have) { c1x += wcur.x; c1y += wcur.y; c1z += wcur.z; c1w += wcur.w; }

          v1x = __fmul_rn(0.7f, v1x) + __fmul_rn(0.3f, c1x);
          sp = (v1x >= 1.0f); s1x = sp ? 1.f : 0.f; if (sp) v1x = 0.f;
          v1y = __fmul_rn(0.7f, v1y) + __fmul_rn(0.3f, c1y);
          sp = (v1y >= 1.0f); s1y = sp ? 1.f : 0.f; if (sp) v1y = 0.f;
          v1z = __fmul_rn(0.7f, v1z) + __fmul_rn(0.3f, c1z);
          sp = (v1z >= 1.0f); s1z = sp ? 1.f : 0.f; if (sp) v1z = 0.f;
          v1w = __fmul_rn(0.7f, v1w) + __fmul_rn(0.3f, c1w);
          sp = (v1w >= 1.0f); s1w = sp ? 1.f : 0.f; if (sp) v1w = 0.f;
        }

        f4 res; res.x = s1x; res.y = s1y; res.z = s1z; res.w = s1w;
        __builtin_nontemporal_store(res, (f4*)&out[(size_t)e*HID + i4]);

        unsigned long long f0 = __ballot(s1x > 0.5f);
        unsigned long long f1 = __ballot(s1y > 0.5f);
        unsigned long long f2 = __ballot(s1z > 0.5f);
        unsigned long long f3 = __ballot(s1w > 0.5f);
        float cacc = bc;
        #define CPROCQ(MASK, Q)                                 \
          mm = (MASK);                                          \
          while (mm) {                                          \
            int l = __builtin_ctzll(mm); mm &= mm - 1;          \
            cacc += WoT[(l*4 + (Q))*COORD_DIM + lane];          \
          }
        CPROCQ(f0, 0)
        CPROCQ(f1, 1)
        CPROCQ(f2, 2)
        CPROCQ(f3, 3)
        #undef CPROCQ
        __builtin_nontemporal_store(cacc,
            &out[(size_t)BATCH_N*HID + (size_t)e*COORD_DIM + lane]);
      }
      // threat bound failed per-i check -> defaults already correct, no store
    }
  }
}

extern "C" void kernel_launch(void* const* d_in, const int* in_sizes, int n_in,
                              void* d_out, int out_size, void* d_ws, size_t ws_size,
                              hipStream_t stream) {
  (void)in_sizes; (void)n_in; (void)out_size; (void)ws_size;
  const float* spk = (const float*)d_in[0];
  const float* crd = (const float*)d_in[1];
  const float* W0  = (const float*)d_in[2];
  const float* b0  = (const float*)d_in[3];
  const float* W1  = (const float*)d_in[4];
  const float* b1  = (const float*)d_in[5];
  const float* Wo  = (const float*)d_in[6];
  const float* bo  = (const float*)d_in[7];
  float* ws  = (float*)d_ws;
  float* out = (float*)d_out;

  hipLaunchKernelGGL(init_kernel, dim3(4096), dim3(256), 0, stream,
                     W0, W1, Wo, bo, ws, out);
  hipLaunchKernelGGL(snn_kernel, dim3(BATCH_N/TILE), dim3(BLOCK), 0, stream,
                     spk, crd, W0, b0, b1, bo, ws, out);
}